// Round 6
// baseline (349.142 us; speedup 1.0000x reference)
//
#include <hip/hip_runtime.h>
#include <hip/hip_bf16.h>

typedef float f32x4 __attribute__((ext_vector_type(4)));
typedef short s16x8 __attribute__((ext_vector_type(8)));
typedef unsigned short u16;
typedef unsigned int u32;
typedef __attribute__((address_space(1))) u32 gu32;
typedef __attribute__((address_space(3))) u32 lu32;

#define NH 12
#define DH 64
#define DM 768
#define S_LEN 2048
#define B_SZ 4

static __device__ __forceinline__ u16 f2bf(float f) {
  __hip_bfloat16 h = __float2bfloat16(f);
  return __builtin_bit_cast(u16, h);
}
static __device__ __forceinline__ s16x8 pack_bf16x8(float4 a, float4 b) {
  s16x8 r;
  r[0] = (short)f2bf(a.x); r[1] = (short)f2bf(a.y);
  r[2] = (short)f2bf(a.z); r[3] = (short)f2bf(a.w);
  r[4] = (short)f2bf(b.x); r[5] = (short)f2bf(b.y);
  r[6] = (short)f2bf(b.z); r[7] = (short)f2bf(b.w);
  return r;
}
// async global->LDS, 16B per lane; LDS dest = wave-uniform base + lane*16
static __device__ __forceinline__ void glds16(const u16* g, u16* l) {
  __builtin_amdgcn_global_load_lds((const gu32*)g, (lu32*)l, 16, 0, 0);
}

// ---------------------------------------------------------------------------
// R6: fused setup kernel — blocks [0,256) build the RoPE cos/sin table,
// blocks [256,4480) do the one-time f32->bf16 conversion (RNE, bit-identical
// to the previous two-kernel version). Saves one dispatch.
// ---------------------------------------------------------------------------
__global__ __launch_bounds__(256) void setup_kernel(
    const float* __restrict__ x, const float* __restrict__ wq,
    const float* __restrict__ wk, const float* __restrict__ wv,
    const float* __restrict__ wo, float2* __restrict__ tab,
    u16* __restrict__ xb, u16* __restrict__ wqb, u16* __restrict__ wkb,
    u16* __restrict__ wvb, u16* __restrict__ wob)
{
  if (blockIdx.x < 256) {                           // RoPE table
    const int idx = blockIdx.x * 256 + threadIdx.x; // 0..65535 exact
    const int sl = idx >> 5, i = idx & 31;
    const float inv_freq = exp2f((float)(2 * i) * (-13.287712379549449f / 64.0f));
    float s, c;
    sincosf((float)sl * inv_freq, &s, &c);
    tab[idx] = make_float2(c, s);
    return;
  }
  const int u = (blockIdx.x - 256) * 256 + threadIdx.x;  // 0..1081343 exact
  const float* src; u16* dst; int off;
  if (u < 786432) {
    src = x; dst = xb; off = u;
  } else {
    const int wu = u - 786432;
    const int w = wu / 73728, o = wu - w * 73728;
    src = (w == 0) ? wq : (w == 1) ? wk : (w == 2) ? wv : wo;
    dst = (w == 0) ? wqb : (w == 1) ? wkb : (w == 2) ? wvb : wob;
    off = o;
  }
  const float4* s = (const float4*)(src + (size_t)off * 8);
  float4 a = s[0], b = s[1];
  *(s16x8*)(dst + (size_t)off * 8) = pack_bf16x8(a, b);
}

// ---------------------------------------------------------------------------
// QKV projection + RoPE — UNCHANGED from R5 (verified; frozen this round).
// ---------------------------------------------------------------------------
#define QSCALE 0.18033688011112042f   // 0.125 * log2(e)

__global__ __launch_bounds__(256) void qkv_rope_kernel(
    const u16* __restrict__ xb, const u16* __restrict__ wqb,
    const u16* __restrict__ wkb, const u16* __restrict__ wvb,
    const float2* __restrict__ tab,
    u16* __restrict__ qo, u16* __restrict__ ko, u16* __restrict__ vo)
{
  const int z = blockIdx.z;                 // 0=q 1=k 2=v
  const u16* Wp = (z == 0) ? wqb : (z == 1) ? wkb : wvb;
  u16* Op = (z == 0) ? qo : (z == 1) ? ko : vo;
  const int mTile = blockIdx.x * 128;
  const int nTile = blockIdx.y * 128;
  const int tid = threadIdx.x;
  const int wave = tid >> 6, lane = tid & 63;
  const int lm = lane & 15, lq = lane >> 4;
  const int wr = wave >> 1, wc = wave & 1;  // 2x2 wave grid over 128x128

  __shared__ u16 Al[128 * 32];
  __shared__ u16 Bl[128 * 32];
  __shared__ u16 Tl[64 * 136];              // v-transpose staging

  f32x4 acc[4][4];
#pragma unroll
  for (int i = 0; i < 4; ++i)
#pragma unroll
    for (int jn = 0; jn < 4; ++jn) acc[i][jn] = (f32x4){0.f, 0.f, 0.f, 0.f};

  const int srA = wave * 16 + (lane >> 2);
  const int scA = (lane & 3) * 8;           // u16 col offset

  for (int k0 = 0; k0 < DM; k0 += 32) {
    __syncthreads();
    glds16(&xb[(size_t)(mTile + srA) * DM + k0 + scA],      &Al[(wave * 16) * 32]);
    glds16(&xb[(size_t)(mTile + 64 + srA) * DM + k0 + scA], &Al[(64 + wave * 16) * 32]);
    glds16(&Wp[(size_t)(nTile + srA) * DM + k0 + scA],      &Bl[(wave * 16) * 32]);
    glds16(&Wp[(size_t)(nTile + 64 + srA) * DM + k0 + scA], &Bl[(64 + wave * 16) * 32]);
    __syncthreads();
    s16x8 af[4], bf[4];
#pragma unroll
    for (int mt = 0; mt < 4; ++mt)
      af[mt] = *(const s16x8*)&Al[(wr * 64 + mt * 16 + lm) * 32 + lq * 8];
#pragma unroll
    for (int nt = 0; nt < 4; ++nt)
      bf[nt] = *(const s16x8*)&Bl[(wc * 64 + nt * 16 + lm) * 32 + lq * 8];
#pragma unroll
    for (int mt = 0; mt < 4; ++mt)
#pragma unroll
      for (int nt = 0; nt < 4; ++nt)
        acc[mt][nt] = __builtin_amdgcn_mfma_f32_16x16x32_bf16(af[mt], bf[nt], acc[mt][nt], 0, 0, 0);
  }

  if (z < 2) {
#pragma unroll
    for (int mt = 0; mt < 4; ++mt)
#pragma unroll
      for (int nt = 0; nt < 4; ++nt)
#pragma unroll
        for (int r = 0; r < 4; ++r) {
          float val = acc[mt][nt][r];
          float partner = __shfl_xor(val, 1);
          const int mI = mTile + wr * 64 + mt * 16 + lq * 4 + r;  // token
          const int nI = nTile + wc * 64 + nt * 16 + lm;          // feature
          const int b = mI >> 11, sl2 = mI & (S_LEN - 1);
          const int h = nI >> 6, dd = nI & 63;
          const float2 cs = tab[sl2 * 32 + (dd >> 1)];
          float res = val * cs.x + partner * ((dd & 1) ? cs.y : -cs.y);
          if (z == 0) res *= QSCALE;
          Op[(((size_t)(b * NH + h)) * S_LEN + sl2) * DH + dd] = f2bf(res);
        }
  } else {
    const int b = mTile >> 11;               // block-uniform (128 | 2048)
    const int sbase = mTile & (S_LEN - 1);
#pragma unroll
    for (int half = 0; half < 2; ++half) {
      __syncthreads();
      if (wc == half) {
#pragma unroll
        for (int mt = 0; mt < 4; ++mt)
#pragma unroll
          for (int nt = 0; nt < 4; ++nt) {
            ushort4 pk;
            pk.x = f2bf(acc[mt][nt][0]);
            pk.y = f2bf(acc[mt][nt][1]);
            pk.z = f2bf(acc[mt][nt][2]);
            pk.w = f2bf(acc[mt][nt][3]);
            *(ushort4*)&Tl[(nt * 16 + lm) * 136 + wr * 64 + mt * 16 + lq * 4] = pk;
          }
      }
      __syncthreads();
      const int f = tid >> 2, cch = (tid & 3) * 32;  // feature, token chunk
      const int nI = nTile + half * 64 + f;
      const int h = nI >> 6, dd = nI & 63;
      u16* vrow = &Op[(((size_t)(b * NH + h)) * DH + dd) * S_LEN + sbase + cch];
      const uint4* ts = (const uint4*)&Tl[f * 136 + cch];
      uint4 t0 = ts[0], t1 = ts[1], t2 = ts[2], t3 = ts[3];
      ((uint4*)vrow)[0] = t0; ((uint4*)vrow)[1] = t1;
      ((uint4*)vrow)[2] = t2; ((uint4*)vrow)[3] = t3;
    }
  }
}

// ---------------------------------------------------------------------------
// MFMA flash attention. R6 restructure: PAIRED q-tiles.
//  - Block p handles q-tiles jA = 31-jj (heavy) and jB = jj (light),
//    jj = p/48: every block computes exactly (jA+1)+(jB+1) = 33 tile-units
//    of MFMA work -> perfect compute balance, no dispatch tail.
//  - The pair SHARES staged K/V: staged tiles per bh drop 528 -> 392 (0.74x).
//  - Grid 768 = exactly 3 blocks/CU, all resident from t=0.
//  - XCD grouping kept: bh = p%48, 48*jj = 0 mod 8 -> one XCD per bh.
//  - 2-deep K/V register prefetch, T13 defer-max, Pl stride 76 kept.
//    Pl is reused g=A then g=B (same-wave DS ordering, no barrier needed).
// ---------------------------------------------------------------------------
#define KVST 72
#define PST 76
#define DEFER_THR 8.0f

__global__ __launch_bounds__(256) void attn_kernel(
    const u16* __restrict__ q, const u16* __restrict__ k,
    const u16* __restrict__ vt, u16* __restrict__ o)
{
  const int p = blockIdx.x;                 // 768 blocks
  const int bh = p % 48;
  const int jj = p / 48;                    // 0..15
  const int jA = 31 - jj;                   // heavy q-tile
  const int jB = jj;                        // light q-tile
  const size_t base = (size_t)bh * S_LEN * DH;
  const int tid = threadIdx.x;
  const int wave = tid >> 6, lane = tid & 63;
  const int lm = lane & 15, lq = lane >> 4;

  __shared__ u16 Kl[64 * KVST];            // [key][d]
  __shared__ u16 Vl[64 * KVST];            // [d][key]
  __shared__ u16 Pl[64 * PST];             // per-wave 16 q-rows x 64 keys

  const int qmA = jA * 64 + wave * 16;
  const int qmB = jB * 64 + wave * 16;

  s16x8 aqA[2], aqB[2];
#pragma unroll
  for (int kk = 0; kk < 2; ++kk) {
    aqA[kk] = *(const s16x8*)&q[base + (size_t)(qmA + lm) * DH + kk * 32 + lq * 8];
    aqB[kk] = *(const s16x8*)&q[base + (size_t)(qmB + lm) * DH + kk * 32 + lq * 8];
  }

  f32x4 OaccA[4], OaccB[4];
  float mA[4], lA[4], mB[4], lB[4];
#pragma unroll
  for (int i = 0; i < 4; ++i) {
    OaccA[i] = (f32x4){0.f, 0.f, 0.f, 0.f};
    OaccB[i] = (f32x4){0.f, 0.f, 0.f, 0.f};
    mA[i] = -1e30f; lA[i] = 0.f;
    mB[i] = -1e30f; lB[i] = 0.f;
  }

  const int srow = tid >> 2, scol16 = (tid & 3) * 16;
  const int ntiles = jA + 1;               // >= 17 always

  // one q-group's tile pass: QK^T -> mask -> online softmax -> PV
  auto compute_g = [&](int t, int qm, s16x8* aq, f32x4* Oacc,
                       float* m_i, float* l_i) {
    f32x4 S[4];
#pragma unroll
    for (int i = 0; i < 4; ++i) S[i] = (f32x4){0.f, 0.f, 0.f, 0.f};
#pragma unroll
    for (int kk = 0; kk < 2; ++kk) {
#pragma unroll
      for (int nt = 0; nt < 4; ++nt) {
        s16x8 kf = *(const s16x8*)&Kl[(nt * 16 + lm) * KVST + kk * 32 + lq * 8];
        S[nt] = __builtin_amdgcn_mfma_f32_16x16x32_bf16(aq[kk], kf, S[nt], 0, 0, 0);
      }
    }

    if (t * 64 + 63 > qm) {                // diagonal tile: causal mask
#pragma unroll
      for (int nt = 0; nt < 4; ++nt)
#pragma unroll
        for (int r = 0; r < 4; ++r) {
          const int keyg = t * 64 + nt * 16 + lm;
          const int qg = qm + lq * 4 + r;
          if (keyg > qg) S[nt][r] = -1e30f;
        }
    }

#pragma unroll
    for (int r = 0; r < 4; ++r) {
      float rm = fmaxf(fmaxf(S[0][r], S[1][r]), fmaxf(S[2][r], S[3][r]));
      rm = fmaxf(rm, __shfl_xor(rm, 1));
      rm = fmaxf(rm, __shfl_xor(rm, 2));
      rm = fmaxf(rm, __shfl_xor(rm, 4));
      rm = fmaxf(rm, __shfl_xor(rm, 8));
      float mn = m_i[r];
      if (__any(rm > mn + DEFER_THR)) {    // wave-uniform rescale branch
        const float mnew = fmaxf(mn, rm);
        const float alpha = exp2f(mn - mnew);
        l_i[r] *= alpha;
#pragma unroll
        for (int nt = 0; nt < 4; ++nt) Oacc[nt][r] *= alpha;
        m_i[r] = mnew;
        mn = mnew;
      }
      float rs = 0.f;
#pragma unroll
      for (int nt = 0; nt < 4; ++nt) {
        float pv = exp2f(S[nt][r] - mn);
        S[nt][r] = pv;
        rs += pv;
      }
      rs += __shfl_xor(rs, 1);
      rs += __shfl_xor(rs, 2);
      rs += __shfl_xor(rs, 4);
      rs += __shfl_xor(rs, 8);
      l_i[r] += rs;
    }

    // P: C-layout regs -> per-wave LDS -> A-layout (same-wave: no barrier)
#pragma unroll
    for (int nt = 0; nt < 4; ++nt)
#pragma unroll
      for (int r = 0; r < 4; ++r)
        Pl[(wave * 16 + lq * 4 + r) * PST + nt * 16 + lm] = f2bf(S[nt][r]);

#pragma unroll
    for (int kk = 0; kk < 2; ++kk) {
      s16x8 pa = *(const s16x8*)&Pl[(wave * 16 + lm) * PST + kk * 32 + lq * 8];
#pragma unroll
      for (int nt = 0; nt < 4; ++nt) {
        s16x8 vf = *(const s16x8*)&Vl[(nt * 16 + lm) * KVST + kk * 32 + lq * 8];
        Oacc[nt] = __builtin_amdgcn_mfma_f32_16x16x32_bf16(pa, vf, Oacc[nt], 0, 0, 0);
      }
    }
  };

  // 2-deep prefetch: set X holds even tiles, set Y odd tiles (ntiles >= 17)
  uint4 kX0, kX1, vX0, vX1, kY0, kY1, vY0, vY1;
  {
    const uint4* kg = (const uint4*)&k[base + (size_t)srow * DH + scol16];
    kX0 = kg[0]; kX1 = kg[1];
    const uint4* vg = (const uint4*)&vt[base + (size_t)srow * S_LEN + scol16];
    vX0 = vg[0]; vX1 = vg[1];
    const uint4* kg1 = (const uint4*)&k[base + (size_t)(64 + srow) * DH + scol16];
    kY0 = kg1[0]; kY1 = kg1[1];
    const uint4* vg1 = (const uint4*)&vt[base + (size_t)srow * S_LEN + 64 + scol16];
    vY0 = vg1[0]; vY1 = vg1[1];
  }

  int t = 0;
  while (t < ntiles) {
    // even tile: stage from X, refill X with tile t+2
    __syncthreads();
    *(uint4*)&Kl[srow * KVST + scol16] = kX0;
    *(uint4*)&Kl[srow * KVST + scol16 + 8] = kX1;
    *(uint4*)&Vl[srow * KVST + scol16] = vX0;
    *(uint4*)&Vl[srow * KVST + scol16 + 8] = vX1;
    if (t + 2 < ntiles) {
      const uint4* kg = (const uint4*)
          &k[base + (size_t)((t + 2) * 64 + srow) * DH + scol16];
      kX0 = kg[0]; kX1 = kg[1];
      const uint4* vg = (const uint4*)
          &vt[base + (size_t)srow * S_LEN + (t + 2) * 64 + scol16];
      vX0 = vg[0]; vX1 = vg[1];
    }
    __syncthreads();
    compute_g(t, qmA, aqA, OaccA, mA, lA);
    if (t <= jB) compute_g(t, qmB, aqB, OaccB, mB, lB);
    ++t;
    if (t >= ntiles) break;

    // odd tile: stage from Y, refill Y with tile t+2
    __syncthreads();
    *(uint4*)&Kl[srow * KVST + scol16] = kY0;
    *(uint4*)&Kl[srow * KVST + scol16 + 8] = kY1;
    *(uint4*)&Vl[srow * KVST + scol16] = vY0;
    *(uint4*)&Vl[srow * KVST + scol16 + 8] = vY1;
    if (t + 2 < ntiles) {
      const uint4* kg = (const uint4*)
          &k[base + (size_t)((t + 2) * 64 + srow) * DH + scol16];
      kY0 = kg[0]; kY1 = kg[1];
      const uint4* vg = (const uint4*)
          &vt[base + (size_t)srow * S_LEN + (t + 2) * 64 + scol16];
      vY0 = vg[0]; vY1 = vg[1];
    }
    __syncthreads();
    compute_g(t, qmA, aqA, OaccA, mA, lA);
    if (t <= jB) compute_g(t, qmB, aqB, OaccB, mB, lB);
    ++t;
  }

  // normalize + store bf16 to aw (b, s, h*64+d) — both q-groups
  const int b = bh / NH, h = bh % NH;
#pragma unroll
  for (int nt = 0; nt < 4; ++nt)
#pragma unroll
    for (int r = 0; r < 4; ++r) {
      const int dd = nt * 16 + lm;
      const int qgA = qmA + lq * 4 + r;
      o[((size_t)(b * S_LEN + qgA)) * DM + h * DH + dd] =
          f2bf(OaccA[nt][r] / lA[r]);
      const int qgB = qmB + lq * 4 + r;
      o[((size_t)(b * S_LEN + qgB)) * DM + h * DH + dd] =
          f2bf(OaccB[nt][r] / lB[r]);
    }
}

// ---------------------------------------------------------------------------
// Out-projection GEMM — UNCHANGED from R5 (verified; frozen this round).
// ---------------------------------------------------------------------------
__global__ __launch_bounds__(256) void out_proj_kernel(
    const u16* __restrict__ a, const u16* __restrict__ wob,
    float* __restrict__ c)
{
  const int mTile = blockIdx.x * 128;
  const int nTile = blockIdx.y * 128;
  const int tid = threadIdx.x;
  const int wave = tid >> 6, lane = tid & 63;
  const int lm = lane & 15, lq = lane >> 4;
  const int wr = wave >> 1, wc = wave & 1;

  __shared__ u16 Al[128 * 32];
  __shared__ u16 Bl[128 * 32];

  f32x4 acc[4][4];
#pragma unroll
  for (int i = 0; i < 4; ++i)
#pragma unroll
    for (int jn = 0; jn < 4; ++jn) acc[i][jn] = (f32x4){0.f, 0.f, 0.f, 0.f};

  const int srA = wave * 16 + (lane >> 2);
  const int scA = (lane & 3) * 8;

  for (int k0 = 0; k0 < DM; k0 += 32) {
    __syncthreads();
    glds16(&a[(size_t)(mTile + srA) * DM + k0 + scA],        &Al[(wave * 16) * 32]);
    glds16(&a[(size_t)(mTile + 64 + srA) * DM + k0 + scA],   &Al[(64 + wave * 16) * 32]);
    glds16(&wob[(size_t)(nTile + srA) * DM + k0 + scA],      &Bl[(wave * 16) * 32]);
    glds16(&wob[(size_t)(nTile + 64 + srA) * DM + k0 + scA], &Bl[(64 + wave * 16) * 32]);
    __syncthreads();
    s16x8 af[4], bf[4];
#pragma unroll
    for (int mt = 0; mt < 4; ++mt)
      af[mt] = *(const s16x8*)&Al[(wr * 64 + mt * 16 + lm) * 32 + lq * 8];
#pragma unroll
    for (int nt = 0; nt < 4; ++nt)
      bf[nt] = *(const s16x8*)&Bl[(wc * 64 + nt * 16 + lm) * 32 + lq * 8];
#pragma unroll
    for (int mt = 0; mt < 4; ++mt)
#pragma unroll
      for (int nt = 0; nt < 4; ++nt)
        acc[mt][nt] = __builtin_amdgcn_mfma_f32_16x16x32_bf16(af[mt], bf[nt], acc[mt][nt], 0, 0, 0);
  }

#pragma unroll
  for (int mt = 0; mt < 4; ++mt)
#pragma unroll
    for (int nt = 0; nt < 4; ++nt)
#pragma unroll
      for (int r = 0; r < 4; ++r)
        c[(size_t)(mTile + wr * 64 + mt * 16 + lq * 4 + r) * DM +
          nTile + wc * 64 + nt * 16 + lm] = acc[mt][nt][r];
}

// ---------------------------------------------------------------------------
extern "C" void kernel_launch(void* const* d_in, const int* in_sizes, int n_in,
                              void* d_out, int out_size, void* d_ws, size_t ws_size,
                              hipStream_t stream) {
  const float* x  = (const float*)d_in[0];   // inputs: float32
  const float* wq = (const float*)d_in[1];
  const float* wk = (const float*)d_in[2];
  const float* wv = (const float*)d_in[3];
  const float* wo = (const float*)d_in[4];
  float* out = (float*)d_out;                // output: float32
  u16* ws  = (u16*)d_ws;

  const size_t QKV = (size_t)B_SZ * S_LEN * DM;  // 6291456 elems
  u16* qw = ws;
  u16* kw = ws + QKV;
  u16* vw = ws + 2 * QKV;                        // v TRANSPOSED (b,h,d,s)
  u16* aw = ws + 3 * QKV;                        // xbf during qkv; attn out after
  float2* tab = (float2*)(ws + 4 * QKV);         // 2048 x 32 cos/sin (512KB)
  u16* wqb = ws + 4 * QKV + 262144;              // bf16 weights (1.18MB each)
  u16* wkb = wqb + 589824;
  u16* wvb = wkb + 589824;
  u16* wob = wvb + 589824;                       // total ws: ~55.6MB

  u16* xbf = aw;                                 // region shared with aw

  setup_kernel<<<dim3(4480), 256, 0, stream>>>(
      x, wq, wk, wv, wo, tab, xbf, wqb, wkb, wvb, wob);
  qkv_rope_kernel<<<dim3(64, 6, 3), 256, 0, stream>>>(
      xbf, wqb, wkb, wvb, tab, qw, kw, vw);
  attn_kernel<<<dim3(16 * 48), 256, 0, stream>>>(qw, kw, vw, aw);
  out_proj_kernel<<<dim3(64, 6), 256, 0, stream>>>(aw, wob, out);
}